// Round 9
// baseline (1786.618 us; speedup 1.0000x reference)
//
#include <hip/hip_runtime.h>

#define N_NODES 100000
#define N_EDGES 600000
#define NGRAPH 512
#define NOPS_T 8
#define EPS_MSG 1e-7f
#define EPS_LN 1e-5f
#define NTILES 6250

typedef unsigned short u16;
typedef unsigned int u32;
typedef __attribute__((ext_vector_type(8))) short short8;   // 8 bf16 (4 VGPRs) MFMA A/B frag
typedef __attribute__((ext_vector_type(4))) float f32x4;    // MFMA C/D frag

__device__ __forceinline__ float bf2f(u16 u) {
    union { float f; u32 i; } v; v.i = ((u32)u) << 16; return v.f;
}
__device__ __forceinline__ u16 f2bf(float f) {
    union { float f; u32 i; } v; v.f = f;
    u32 r = (v.i + 0x7fffu + ((v.i >> 16) & 1u)) >> 16;   // RNE
    return (u16)r;
}
__device__ __forceinline__ float wave_sum(float v) {
    #pragma unroll
    for (int off = 32; off > 0; off >>= 1) v += __shfl_xor(v, off, 64);
    return v;
}

// =============== prep: bf16 transposed weights (n-major, k contiguous) ===============
__global__ __launch_bounds__(256) void k_prep(const float* __restrict__ W1,
                                              const float* __restrict__ W2,
                                              u16* __restrict__ tW1,
                                              u16* __restrict__ tW2) {
    int i = blockIdx.x * 256 + threadIdx.x;   // over 4*32768
    if (i >= 4 * 32768) return;
    int l = i >> 15, r = i & 32767;
    int n1 = r >> 7, k1 = r & 127;
    tW1[i] = f2bf(W1[(l << 15) + k1 * 256 + n1]);
    int n2 = r >> 8, k2 = r & 255;
    tW2[i] = f2bf(W2[(l << 15) + k2 * 128 + n2]);
}

// =============== encoder: h2 = bf16(x @ We + be)  (r4-proven layout) ===============
__global__ __launch_bounds__(256, 1) void k_enc(const float* __restrict__ x,
                                                const float* __restrict__ We,
                                                const float* __restrict__ be,
                                                u16* __restrict__ h2) {
    __shared__ __align__(16) u16 sWe[128 * 136];   // We^T padded (+8): row n, k contiguous
    __shared__ float sB[128];
    int tid = threadIdx.x;
    for (int i = tid; i < 128 * 128; i += 256) { int k = i >> 7, n = i & 127; sWe[n * 136 + k] = f2bf(We[i]); }
    if (tid < 128) sB[tid] = be[tid];
    __syncthreads();
    int wave = tid >> 6, lane = tid & 63, q = lane >> 4, c = lane & 15;
    for (int tile = blockIdx.x * 4 + wave; tile < NTILES; tile += gridDim.x * 4) {
        int n0 = tile * 16;
        const float4* xp = (const float4*)(x + (size_t)(n0 + c) * 128);
        short8 af[4];
        #pragma unroll
        for (int ks = 0; ks < 4; ks++) {
            float4 v0 = xp[ks * 8 + q * 2], v1 = xp[ks * 8 + q * 2 + 1];
            short8 a;
            a[0] = (short)f2bf(v0.x); a[1] = (short)f2bf(v0.y);
            a[2] = (short)f2bf(v0.z); a[3] = (short)f2bf(v0.w);
            a[4] = (short)f2bf(v1.x); a[5] = (short)f2bf(v1.y);
            a[6] = (short)f2bf(v1.z); a[7] = (short)f2bf(v1.w);
            af[ks] = a;
        }
        f32x4 acc[8];
        #pragma unroll
        for (int t = 0; t < 8; t++) {
            float bias = sB[t * 16 + c];
            f32x4 a4 = {bias, bias, bias, bias};
            const short8* bp = (const short8*)(sWe + (t * 16 + c) * 136);
            #pragma unroll
            for (int ks = 0; ks < 4; ks++)
                a4 = __builtin_amdgcn_mfma_f32_16x16x32_bf16(af[ks], bp[ks * 4 + q], a4, 0, 0, 0);
            acc[t] = a4;
        }
        u16* h2b = h2 + (size_t)n0 * 128;
        #pragma unroll
        for (int t = 0; t < 8; t++)
            #pragma unroll
            for (int i = 0; i < 4; i++) {
                int idx = (q * 4 + i) * 128 + t * 16 + c;     // D: row=q*4+i (node), col=t*16+c (chan)
                h2b[idx] = f2bf(acc[t][i]);
            }
    }
}

// =============== CSR build (once per launch; edges static across layers) ===============
__global__ __launch_bounds__(256) void k_hist(const int* __restrict__ ei, int* __restrict__ deg) {
    int e = blockIdx.x * 256 + threadIdx.x;
    if (e < N_EDGES) atomicAdd(&deg[ei[N_EDGES + e]], 1);
}

__global__ __launch_bounds__(256) void k_scan1(const int* __restrict__ deg,
                                               int* __restrict__ offs,
                                               int* __restrict__ bsum) {
    __shared__ int swv[4];
    int b = blockIdx.x, t = threadIdx.x;
    int base = b * 1024 + t * 4;
    int4 v = {0, 0, 0, 0};
    if (base < N_NODES) v = *(const int4*)(deg + base);   // N_NODES % 4 == 0
    int s = v.x + v.y + v.z + v.w;
    int lane = t & 63, wid = t >> 6;
    int incl = s;
    #pragma unroll
    for (int off = 1; off < 64; off <<= 1) {
        int o = __shfl_up(incl, off, 64);
        if (lane >= off) incl += o;
    }
    if (lane == 63) swv[wid] = incl;
    __syncthreads();
    int wbase = 0;
    #pragma unroll
    for (int w = 0; w < 4; w++) if (w < wid) wbase += swv[w];
    int ex = wbase + incl - s;
    if (base < N_NODES) {
        offs[base]     = ex;
        offs[base + 1] = ex + v.x;
        offs[base + 2] = ex + v.x + v.y;
        offs[base + 3] = ex + v.x + v.y + v.z;
    }
    if (t == 255) bsum[b] = wbase + incl;
}

__global__ __launch_bounds__(128) void k_scan2(int* __restrict__ bsum, int nb) {
    __shared__ int s[128];
    int t = threadIdx.x;
    int v = t < nb ? bsum[t] : 0;
    s[t] = v;
    __syncthreads();
    for (int off = 1; off < 128; off <<= 1) {
        int a = t >= off ? s[t - off] : 0;
        __syncthreads();
        s[t] += a;
        __syncthreads();
    }
    if (t < nb) bsum[t] = s[t] - v;
}

__global__ __launch_bounds__(256) void k_scan3(int* __restrict__ offs,
                                               const int* __restrict__ bsum,
                                               int* __restrict__ cursor) {
    int b = blockIdx.x, t = threadIdx.x;
    int base = b * 1024 + t * 4;
    if (base >= N_NODES) return;
    int add = bsum[b];
    #pragma unroll
    for (int i = 0; i < 4; i++) {
        int o = offs[base + i] + add;
        offs[base + i] = o;
        cursor[base + i] = o;
    }
}

__global__ __launch_bounds__(256) void k_scatter(const int* __restrict__ ei,
                                                 const int* __restrict__ ea,
                                                 int* __restrict__ cursor,
                                                 int* __restrict__ csr) {
    int e = blockIdx.x * 256 + threadIdx.x;
    if (e >= N_EDGES) return;
    int s = ei[e], d = ei[N_EDGES + e], a = ea[e];
    int pos = atomicAdd(&cursor[d], 1);
    csr[pos] = s | (a << 24);                 // src < 2^17, attr < 8
}

// =============== aggregate (gather, no atomics): xin = bf16(h2 + sum msgs) ===============
__global__ __launch_bounds__(256) void k_agg(const int* __restrict__ offs,
                                             const int* __restrict__ deg,
                                             const int* __restrict__ csr,
                                             const float* __restrict__ Et,
                                             const u16* __restrict__ h2,
                                             u16* __restrict__ xin) {
    __shared__ float4 sE[NOPS_T * 32];
    int tid = threadIdx.x;
    sE[tid] = ((const float4*)Et)[tid];
    __syncthreads();
    int n = blockIdx.x * 8 + (tid >> 5);
    if (n >= N_NODES) return;
    int g = tid & 31;
    float a0 = 0.f, a1 = 0.f, a2 = 0.f, a3 = 0.f;
    int st = offs[n], dg = deg[n];
    int j = 0;
    for (; j + 4 <= dg; j += 4) {               // 4 edges in flight
        int p0 = csr[st + j], p1 = csr[st + j + 1], p2 = csr[st + j + 2], p3 = csr[st + j + 3];
        uint2 h0 = *(const uint2*)(h2 + (size_t)(p0 & 0xFFFFFF) * 128 + g * 4);
        uint2 h1 = *(const uint2*)(h2 + (size_t)(p1 & 0xFFFFFF) * 128 + g * 4);
        uint2 h2v = *(const uint2*)(h2 + (size_t)(p2 & 0xFFFFFF) * 128 + g * 4);
        uint2 h3 = *(const uint2*)(h2 + (size_t)(p3 & 0xFFFFFF) * 128 + g * 4);
        float4 e0 = sE[(((u32)p0) >> 24) * 32 + g];
        float4 e1 = sE[(((u32)p1) >> 24) * 32 + g];
        float4 e2 = sE[(((u32)p2) >> 24) * 32 + g];
        float4 e3 = sE[(((u32)p3) >> 24) * 32 + g];
        a0 += fmaxf(bf2f((u16)(h0.x & 0xffff)) + e0.x, 0.f) + EPS_MSG;
        a1 += fmaxf(bf2f((u16)(h0.x >> 16))    + e0.y, 0.f) + EPS_MSG;
        a2 += fmaxf(bf2f((u16)(h0.y & 0xffff)) + e0.z, 0.f) + EPS_MSG;
        a3 += fmaxf(bf2f((u16)(h0.y >> 16))    + e0.w, 0.f) + EPS_MSG;
        a0 += fmaxf(bf2f((u16)(h1.x & 0xffff)) + e1.x, 0.f) + EPS_MSG;
        a1 += fmaxf(bf2f((u16)(h1.x >> 16))    + e1.y, 0.f) + EPS_MSG;
        a2 += fmaxf(bf2f((u16)(h1.y & 0xffff)) + e1.z, 0.f) + EPS_MSG;
        a3 += fmaxf(bf2f((u16)(h1.y >> 16))    + e1.w, 0.f) + EPS_MSG;
        a0 += fmaxf(bf2f((u16)(h2v.x & 0xffff)) + e2.x, 0.f) + EPS_MSG;
        a1 += fmaxf(bf2f((u16)(h2v.x >> 16))    + e2.y, 0.f) + EPS_MSG;
        a2 += fmaxf(bf2f((u16)(h2v.y & 0xffff)) + e2.z, 0.f) + EPS_MSG;
        a3 += fmaxf(bf2f((u16)(h2v.y >> 16))    + e2.w, 0.f) + EPS_MSG;
        a0 += fmaxf(bf2f((u16)(h3.x & 0xffff)) + e3.x, 0.f) + EPS_MSG;
        a1 += fmaxf(bf2f((u16)(h3.x >> 16))    + e3.y, 0.f) + EPS_MSG;
        a2 += fmaxf(bf2f((u16)(h3.y & 0xffff)) + e3.z, 0.f) + EPS_MSG;
        a3 += fmaxf(bf2f((u16)(h3.y >> 16))    + e3.w, 0.f) + EPS_MSG;
    }
    for (; j < dg; j++) {
        int p = csr[st + j];
        int s = p & 0xFFFFFF;
        int a = ((u32)p) >> 24;
        uint2 hv = *(const uint2*)(h2 + (size_t)s * 128 + g * 4);
        float4 ev = sE[a * 32 + g];
        a0 += fmaxf(bf2f((u16)(hv.x & 0xffff)) + ev.x, 0.f) + EPS_MSG;
        a1 += fmaxf(bf2f((u16)(hv.x >> 16))    + ev.y, 0.f) + EPS_MSG;
        a2 += fmaxf(bf2f((u16)(hv.y & 0xffff)) + ev.z, 0.f) + EPS_MSG;
        a3 += fmaxf(bf2f((u16)(hv.y >> 16))    + ev.w, 0.f) + EPS_MSG;
    }
    uint2 hd = *(const uint2*)(h2 + (size_t)n * 128 + g * 4);
    u32 o0 = (u32)f2bf(bf2f((u16)(hd.x & 0xffff)) + a0) |
             ((u32)f2bf(bf2f((u16)(hd.x >> 16))   + a1) << 16);
    u32 o1 = (u32)f2bf(bf2f((u16)(hd.y & 0xffff)) + a2) |
             ((u32)f2bf(bf2f((u16)(hd.y >> 16))   + a3) << 16);
    uint2 o = {o0, o1};
    *(uint2*)(xin + (size_t)n * 128 + g * 4) = o;
}

// =============== MLP stage 1: y = bf16(relu(LN(xin @ W1 + b1))) ===============
// Only W1^T in LDS (80.9 KB total -> 2 blocks/CU at 512 thr = 16 waves/CU).
// y stored in A-frag-ready layout: per tile 4096 u16 (16 nodes x 256 chans),
// 8 chunks x (64 lanes x 8 u16) coalesced 1KB stores.
__global__ __launch_bounds__(512, 4) void k_mlp1(
    const u16* __restrict__ xin, const u16* __restrict__ tW1,
    const float* __restrict__ b1, const float* __restrict__ g1,
    const float* __restrict__ bb1, u16* __restrict__ ybuf) {
    __shared__ __align__(16) u16 sW1[256 * 136];   // 69632 B
    __shared__ __align__(16) u16 sY[8][16 * 32];   // 8192 B: per-wave 16 nodes x 32 chans
    __shared__ float sP[768];                      // b1|g1|bb1  3072 B
    int tid = threadIdx.x;
    for (int i = tid; i < 4096; i += 512) {
        int n = i >> 4, k8 = (i & 15) << 3;
        *(short8*)(sW1 + n * 136 + k8) = *(const short8*)(tW1 + n * 128 + k8);
    }
    if (tid < 256) { sP[tid] = b1[tid]; sP[256 + tid] = g1[tid]; sP[512 + tid] = bb1[tid]; }
    __syncthreads();

    int wave = tid >> 6, lane = tid & 63, q = lane >> 4, c = lane & 15;
    u16* yst = sY[wave];
    for (int tile = blockIdx.x * 8 + wave; tile < NTILES; tile += gridDim.x * 8) {
        int n0 = tile * 16;
        const short8* xp = (const short8*)(xin + (size_t)(n0 + c) * 128);
        short8 af[4];
        #pragma unroll
        for (int ks = 0; ks < 4; ks++) af[ks] = xp[ks * 4 + q];
        // GEMM1 (bias in C-init)
        f32x4 acc[16];
        #pragma unroll
        for (int t = 0; t < 16; t++) {
            float bias = sP[t * 16 + c];
            f32x4 a4 = {bias, bias, bias, bias};
            const short8* bp = (const short8*)(sW1 + (t * 16 + c) * 136);
            #pragma unroll
            for (int ks = 0; ks < 4; ks++)
                a4 = __builtin_amdgcn_mfma_f32_16x16x32_bf16(af[ks], bp[ks * 4 + q], a4, 0, 0, 0);
            acc[t] = a4;
        }
        // LN over 256 (rows live in one quad)
        float sm[4] = {0, 0, 0, 0}, sq[4] = {0, 0, 0, 0};
        #pragma unroll
        for (int t = 0; t < 16; t++)
            #pragma unroll
            for (int i = 0; i < 4; i++) { float v = acc[t][i]; sm[i] += v; sq[i] += v * v; }
        #pragma unroll
        for (int i = 0; i < 4; i++)
            #pragma unroll
            for (int m = 1; m < 16; m <<= 1) { sm[i] += __shfl_xor(sm[i], m, 64); sq[i] += __shfl_xor(sq[i], m, 64); }
        float mean[4], rs[4];
        #pragma unroll
        for (int i = 0; i < 4; i++) {
            mean[i] = sm[i] * (1.f / 256.f);
            float var = fmaxf(sq[i] * (1.f / 256.f) - mean[i] * mean[i], 0.f);
            rs[i] = rsqrtf(var + EPS_LN);
        }
        // emit y in A-frag layout: 8 chunks of 32 chans via wave-private LDS
        u16* yo = ybuf + (size_t)tile * 4096;      // 4096 u16 per tile (16 nodes x 256 chans)
        #pragma unroll
        for (int ks2 = 0; ks2 < 8; ks2++) {
            #pragma unroll
            for (int tt = 0; tt < 2; tt++) {
                int t = ks2 * 2 + tt;
                int n = t * 16 + c;
                float gg = sP[256 + n], bb = sP[512 + n];
                #pragma unroll
                for (int i = 0; i < 4; i++) {
                    float v = fmaxf(gg * (acc[t][i] - mean[i]) * rs[i] + bb, 0.f);
                    yst[(q * 4 + i) * 32 + tt * 16 + c] = f2bf(v);
                }
            }
            short8 a2 = *(const short8*)(yst + c * 32 + q * 8);   // node c, 8 chans
            *(short8*)(yo + ks2 * 512 + lane * 8) = a2;           // coalesced 1KB/instr
        }
    }
}

// =============== MLP stage 2: h' = y @ W2 + b2 (+h); h2 = bf16(relu(LN(h'))) ===============
// Only W2^T in LDS (69.1 KB -> 2 blocks/CU). A-frags straight from ybuf (coalesced).
__global__ __launch_bounds__(512, 4) void k_mlp2(
    const u16* __restrict__ ybuf, float* __restrict__ h,
    const u16* __restrict__ tW2, const float* __restrict__ b2,
    const float* __restrict__ gno, const float* __restrict__ bno,
    u16* __restrict__ h2_out, const int* __restrict__ batch,
    float* __restrict__ pool, float* __restrict__ cnt,
    int resid, int do_pool) {
    __shared__ __align__(16) u16 sW2[128 * 264];   // 67584 B
    __shared__ float sP[384];                      // b2|gno|bno 1536 B
    int tid = threadIdx.x;
    for (int i = tid; i < 4096; i += 512) {
        int n = i >> 5, k8 = (i & 31) << 3;
        *(short8*)(sW2 + n * 264 + k8) = *(const short8*)(tW2 + n * 256 + k8);
    }
    if (tid < 128) { sP[tid] = b2[tid]; sP[128 + tid] = gno[tid]; sP[256 + tid] = bno[tid]; }
    __syncthreads();

    int wave = tid >> 6, lane = tid & 63, q = lane >> 4, c = lane & 15;
    for (int tile = blockIdx.x * 8 + wave; tile < NTILES; tile += gridDim.x * 8) {
        int n0 = tile * 16;
        // A fragments from ybuf (coalesced 16B/lane)
        const u16* yo = ybuf + (size_t)tile * 4096;
        short8 ay[8];
        #pragma unroll
        for (int ks2 = 0; ks2 < 8; ks2++) ay[ks2] = *(const short8*)(yo + ks2 * 512 + lane * 8);
        // residual prefetch (quad-coalesced 64B segments)
        float rr[8][4];
        float* hb = h + (size_t)n0 * 128;
        if (resid) {
            #pragma unroll
            for (int t2 = 0; t2 < 8; t2++)
                #pragma unroll
                for (int i = 0; i < 4; i++) rr[t2][i] = hb[(q * 4 + i) * 128 + t2 * 16 + c];
        }
        // GEMM2 (bias in C-init)
        f32x4 acc2[8];
        #pragma unroll
        for (int t2 = 0; t2 < 8; t2++) {
            float bias = sP[t2 * 16 + c];
            f32x4 a4 = {bias, bias, bias, bias};
            const short8* bp2 = (const short8*)(sW2 + (t2 * 16 + c) * 264);
            #pragma unroll
            for (int ks2 = 0; ks2 < 8; ks2++)
                a4 = __builtin_amdgcn_mfma_f32_16x16x32_bf16(ay[ks2], bp2[ks2 * 4 + q], a4, 0, 0, 0);
            acc2[t2] = a4;
        }
        // epilogue: (+resid), LN over 128
        float sm2[4] = {0, 0, 0, 0}, sq2[4] = {0, 0, 0, 0};
        float vout[8][4];
        #pragma unroll
        for (int t2 = 0; t2 < 8; t2++)
            #pragma unroll
            for (int i = 0; i < 4; i++) {
                float v = acc2[t2][i];
                if (resid) v += rr[t2][i];
                vout[t2][i] = v; sm2[i] += v; sq2[i] += v * v;
            }
        #pragma unroll
        for (int i = 0; i < 4; i++)
            #pragma unroll
            for (int m = 1; m < 16; m <<= 1) { sm2[i] += __shfl_xor(sm2[i], m, 64); sq2[i] += __shfl_xor(sq2[i], m, 64); }
        float mean2[4], rs2[4];
        #pragma unroll
        for (int i = 0; i < 4; i++) {
            mean2[i] = sm2[i] * (1.f / 128.f);
            float var = fmaxf(sq2[i] * (1.f / 128.f) - mean2[i] * mean2[i], 0.f);
            rs2[i] = rsqrtf(var + EPS_LN);
        }
        if (!do_pool) {
            u16* h2b = h2_out + (size_t)n0 * 128;
            #pragma unroll
            for (int t2 = 0; t2 < 8; t2++)
                #pragma unroll
                for (int i = 0; i < 4; i++) {
                    int col = t2 * 16 + c, idx = (q * 4 + i) * 128 + col;
                    float v = vout[t2][i];
                    hb[idx] = v;                                  // residual for next layer
                    float o = sP[128 + col] * (v - mean2[i]) * rs2[i] + sP[256 + col];
                    h2b[idx] = f2bf(fmaxf(o, 0.f));               // next conv input
                }
        } else {
            int bg[4];
            #pragma unroll
            for (int i = 0; i < 4; i++) bg[i] = batch[n0 + q * 4 + i];
            #pragma unroll
            for (int t2 = 0; t2 < 8; t2++)
                #pragma unroll
                for (int i = 0; i < 4; i++) {
                    int col = t2 * 16 + c;
                    float o = sP[128 + col] * (vout[t2][i] - mean2[i]) * rs2[i] + sP[256 + col];
                    unsafeAtomicAdd(&pool[(size_t)bg[i] * 128 + col], o);
                }
            if (c == 0)
                #pragma unroll
                for (int i = 0; i < 4; i++) unsafeAtomicAdd(&cnt[bg[i]], 1.f);
        }
    }
}

// =============== readout: sigmoid(mean_pool @ Wp + bp) ===============
__global__ __launch_bounds__(64) void k_read(const float* __restrict__ pool,
                                             const float* __restrict__ cnt,
                                             const float* __restrict__ Wp,
                                             const float* __restrict__ bp,
                                             float* __restrict__ out) {
    int g = blockIdx.x, lane = threadIdx.x;
    float inv = 1.f / fmaxf(cnt[g], 1.f);
    float d = (pool[(size_t)g * 128 + lane] * Wp[lane] +
               pool[(size_t)g * 128 + 64 + lane] * Wp[64 + lane]) * inv;
    float s = wave_sum(d);
    if (lane == 0) out[g] = 1.f / (1.f + expf(-(s + bp[0])));
}

extern "C" void kernel_launch(void* const* d_in, const int* in_sizes, int n_in,
                              void* d_out, int out_size, void* d_ws, size_t ws_size,
                              hipStream_t stream) {
    const float* x   = (const float*)d_in[0];
    const int*   ei  = (const int*)d_in[1];
    const int*   ea  = (const int*)d_in[2];
    const int*   bat = (const int*)d_in[3];
    const float* We  = (const float*)d_in[4];
    const float* be  = (const float*)d_in[5];
    const float* Et  = (const float*)d_in[6];
    const float* W1  = (const float*)d_in[7];
    const float* b1  = (const float*)d_in[8];
    const float* g1  = (const float*)d_in[9];
    const float* bb1 = (const float*)d_in[10];
    const float* W2  = (const float*)d_in[11];
    const float* b2  = (const float*)d_in[12];
    const float* gn  = (const float*)d_in[13];
    const float* bn  = (const float*)d_in[14];
    const float* Wp  = (const float*)d_in[15];
    const float* bp  = (const float*)d_in[16];
    float* out = (float*)d_out;

    char* w = (char*)d_ws;
    float* h    = (float*)w;  w += (size_t)N_NODES * 128 * 4;
    u16*   h2   = (u16*)w;    w += (size_t)N_NODES * 128 * 2;
    u16*   xin  = (u16*)w;    w += (size_t)N_NODES * 128 * 2;
    u16*   ybuf = (u16*)w;    w += (size_t)NTILES * 4096 * 2;
    float* pool = (float*)w;  w += (size_t)NGRAPH * 128 * 4;
    float* cnt  = (float*)w;  w += (size_t)NGRAPH * 4;
    int*   deg  = (int*)w;    w += (size_t)N_NODES * 4;
    int*   offs = (int*)w;    w += (size_t)N_NODES * 4;
    int*   curs = (int*)w;    w += (size_t)N_NODES * 4;
    int*   bsum = (int*)w;    w += 128 * 4;
    int*   csr  = (int*)w;    w += (size_t)N_EDGES * 4;
    u16*   tW1  = (u16*)w;    w += (size_t)4 * 32768 * 2;
    u16*   tW2  = (u16*)w;    w += (size_t)4 * 32768 * 2;

    const int NB_SCAN = (N_NODES + 1023) / 1024;   // 98

    hipMemsetAsync(pool, 0, ((size_t)NGRAPH * 128 + NGRAPH) * 4, stream);
    hipMemsetAsync(deg, 0, (size_t)N_NODES * 4, stream);
    k_prep<<<512, 256, 0, stream>>>(W1, W2, tW1, tW2);
    // CSR build (edges are static across layers — build once per launch)
    k_hist<<<(N_EDGES + 255) / 256, 256, 0, stream>>>(ei, deg);
    k_scan1<<<NB_SCAN, 256, 0, stream>>>(deg, offs, bsum);
    k_scan2<<<1, 128, 0, stream>>>(bsum, NB_SCAN);
    k_scan3<<<NB_SCAN, 256, 0, stream>>>(offs, bsum, curs);
    k_scatter<<<(N_EDGES + 255) / 256, 256, 0, stream>>>(ei, ea, curs, csr);

    k_enc<<<256, 256, 0, stream>>>(x, We, be, h2);
    for (int l = 0; l < 4; l++) {
        k_agg<<<(N_NODES + 7) / 8, 256, 0, stream>>>(offs, deg, csr, Et, h2, xin);
        k_mlp1<<<1024, 512, 0, stream>>>(xin, tW1 + (size_t)l * 32768,
                                         b1 + l * 256, g1 + l * 256, bb1 + l * 256, ybuf);
        k_mlp2<<<1024, 512, 0, stream>>>(ybuf, h,
                                         tW2 + (size_t)l * 32768, b2 + l * 128,
                                         gn + l * 128, bn + l * 128,
                                         h2, bat, pool, cnt,
                                         l > 0 ? 1 : 0, l == 3 ? 1 : 0);
    }
    k_read<<<NGRAPH, 64, 0, stream>>>(pool, cnt, Wp, bp, out);
}